// Round 11
// baseline (809.429 us; speedup 1.0000x reference)
//
#include <hip/hip_runtime.h>
#include <hip/hip_bf16.h>

#define N_NODES 100000
#define N_EDGES 1600000
#define F_IN 128
#define HID 64
#define N_GRAPHS 1024

// fine dst-partition for CSR build: bucket = dst>>9 (512 nodes/bucket)
#define SH 9
#define NBU 196        // buckets used: ceil(100000/512)
#define NB 200         // allocated
#define BCAP 9728      // mean 8192 + 17 sigma

// slice-major intermediate layout: buf[s][node][8 bf16], s in [0,8)
#define SLICE_E 800000     // ushorts per slice
#define SLICE_U 400000     // uints per slice

typedef __attribute__((ext_vector_type(8))) short bf16x8;
typedef __attribute__((ext_vector_type(4))) float f32x4;
typedef __attribute__((ext_vector_type(4))) unsigned int u32x4;

// ---------------- bf16 bit helpers --------------------------------------------
__device__ __forceinline__ unsigned short f2bf(float f) {
    __hip_bfloat16 h = __float2bfloat16(f);   // RNE
    return *reinterpret_cast<unsigned short*>(&h);
}
__device__ __forceinline__ float bf2f(unsigned int u) {
    return __uint_as_float(u << 16);
}

// ---------------- dual-path load helpers (wire dtype resolved at runtime) -----
__device__ __forceinline__ float loadf(const void* p, size_t i, int f32) {
    if (f32) return ((const float*)p)[i];
    return __bfloat162float(((const __hip_bfloat16*)p)[i]);
}
__device__ __forceinline__ int loadi(const void* p, size_t i, int i64) {
    if (i64) return (int)((const long long*)p)[i];
    return ((const int*)p)[i];
}

// ---------------- init: wire detect + zero small counters ---------------------
__global__ void k_init(const unsigned int* __restrict__ xw_,
                       const unsigned int* __restrict__ ei_,
                       int* __restrict__ flags,
                       int* __restrict__ gcnt, int* __restrict__ bcnt) {
    __shared__ int cnt_f, cnt_i;
    int t = threadIdx.x;
    if (t == 0) { cnt_f = 0; cnt_i = 0; }
    __syncthreads();
    unsigned int w = xw_[t];
    unsigned int e = (w >> 7) & 0xFFu;
    if (e >= 100u && e <= 140u) atomicAdd(&cnt_f, 1);
    unsigned int iw = ei_[2 * t + 1];
    if (iw == 0u) atomicAdd(&cnt_i, 1);
    for (int i = t; i < N_GRAPHS; i += 256) gcnt[i] = 0;
    for (int i = t; i < NB; i += 256) bcnt[i] = 0;
    __syncthreads();
    if (t == 0) {
        flags[0] = (cnt_f < 180) ? 1 : 0;   // 1 => fp32 wire
        flags[1] = (cnt_i >= 128) ? 1 : 0;  // 1 => int64 wire
    }
}

// ---------------- phase A: partition by dst>>9  (+ fused batch count) ---------
// packed entry: (src << 9) | (dst & 511)  -- 26 bits. PLAIN stores (NT stores
// here caused 77 MB write-amp in R10 -- partial lines bypass L2 merging).
__global__ __launch_bounds__(256) void k_part(const void* __restrict__ ei,
                                              const void* __restrict__ batch,
                                              int* __restrict__ bcnt,
                                              int* __restrict__ gcnt,
                                              unsigned int* __restrict__ packed,
                                              const int* __restrict__ flags) {
    int I64 = flags[1];
    __shared__ int hist[NB];
    __shared__ int base[NB];
    int t = threadIdx.x;
    if (t < NB) hist[t] = 0;
    {
        int n = blockIdx.x * 256 + t;
        if (n < N_NODES) atomicAdd(&gcnt[loadi(batch, n, I64)], 1);
    }
    __syncthreads();
    int e0 = blockIdx.x * 1024;
    int b[4], r[4];
    unsigned int pk[4];
    for (int it = 0; it < 4; ++it) {
        int e = e0 + it * 256 + t;
        b[it] = -1;
        if (e < N_EDGES) {
            int s = loadi(ei, e, I64);
            int d = loadi(ei, (size_t)N_EDGES + e, I64);
            b[it] = d >> SH;
            pk[it] = ((unsigned int)s << SH) | (unsigned int)(d & 511);
            r[it] = atomicAdd(&hist[b[it]], 1);   // LDS rank
        }
    }
    __syncthreads();
    if (t < NB) base[t] = hist[t] ? atomicAdd(&bcnt[t], hist[t]) : 0;
    __syncthreads();
    for (int it = 0; it < 4; ++it) {
        if (b[it] >= 0) {
            int pos = base[b[it]] + r[it];
            if (pos < BCAP) packed[(size_t)b[it] * BCAP + pos] = pk[it];
        }
    }
}

// ---------------- hist: in-degree + dis + scan partials (fused) ---------------
__global__ __launch_bounds__(256) void k_hist(const unsigned int* __restrict__ packed,
                                              const int* __restrict__ bcnt,
                                              int* __restrict__ cnt,
                                              float* __restrict__ dis,
                                              int* __restrict__ partN) {
    __shared__ int hist[512];
    int b = blockIdx.x;
    int t = threadIdx.x;
    int n = bcnt[b];
    if (n > BCAP) n = BCAP;
    for (int i = t; i < 512; i += 256) hist[i] = 0;
    __syncthreads();
    const unsigned int* pb = packed + (size_t)b * BCAP;
    for (int i = t; i < n; i += 256)
        atomicAdd(&hist[pb[i] & 511u], 1);
    __syncthreads();
    int nbase = b << SH;
    for (int i = t; i < 512; i += 256) {
        int node = nbase + i;
        if (node < N_NODES) {
            int c = hist[i];
            cnt[node] = c;
            dis[node] = rsqrtf((float)c + 1.0f);
        }
    }
    __syncthreads();
    for (int off = 128; off > 0; off >>= 1) {
        if (t < off) { hist[t] += hist[t + off]; hist[256 + t] += hist[256 + t + off]; }
        __syncthreads();
    }
    if (t == 0) {
        partN[2 * b] = hist[0];
        if (2 * b + 1 < 391) partN[2 * b + 1] = hist[256];
    }
}

// ---------------- middle scan: partN (391) + graph scan (1024), one block -----
__global__ void k_scan_mid(int* __restrict__ partial, int nb,
                           int* __restrict__ rp, int n,
                           const int* __restrict__ gcnt, int* __restrict__ gptr) {
    __shared__ int s[512];
    int t = threadIdx.x;
    int v = (t < nb) ? partial[t] : 0;
    s[t] = v;
    __syncthreads();
    for (int off = 1; off < 512; off <<= 1) {
        int x = (t >= off) ? s[t - off] : 0;
        __syncthreads();
        s[t] += x;
        __syncthreads();
    }
    if (t < nb) partial[t] = s[t] - v;   // exclusive
    if (t == 511) rp[n] = s[511];        // grand total
    __syncthreads();
    int a = gcnt[2 * t], bq = gcnt[2 * t + 1];
    int ps = a + bq;
    s[t] = ps;
    __syncthreads();
    for (int off = 1; off < 512; off <<= 1) {
        int x = (t >= off) ? s[t - off] : 0;
        __syncthreads();
        s[t] += x;
        __syncthreads();
    }
    int excl = s[t] - ps;
    gptr[2 * t] = excl;
    gptr[2 * t + 1] = excl + a;
    if (t == 511) gptr[1024] = s[511];
}

// ---------------- scan p3: per-256-chunk local scan + offset -> rp ------------
__global__ void k_scan_p3(const int* __restrict__ in, const int* __restrict__ partial,
                          int* __restrict__ out, int n) {
    __shared__ int s[256];
    int t = threadIdx.x;
    int i = blockIdx.x * 256 + t;
    int v = (i < n) ? in[i] : 0;
    s[t] = v;
    __syncthreads();
    for (int off = 1; off < 256; off <<= 1) {
        int x = (t >= off) ? s[t - off] : 0;
        __syncthreads();
        s[t] += x;
        __syncthreads();
    }
    if (i < n) out[i] = partial[blockIdx.x] + s[t] - v;
}

// ---------------- phase B: LDS counting-sort, dense csr writes ----------------
__global__ __launch_bounds__(512) void k_bucketcsr(const unsigned int* __restrict__ packed,
                                                   const int* __restrict__ bcnt,
                                                   const int* __restrict__ rp,
                                                   int* __restrict__ csr) {
    __shared__ int offs[512];
    __shared__ int elds[BCAP];    // 38 KB
    int b = blockIdx.x;
    int nbase = b << SH;
    int base = rp[nbase];
    int lim = nbase + 512; if (lim > N_NODES) lim = N_NODES;
    int nedge = rp[lim] - base;
    if (nedge > BCAP) nedge = BCAP;
    for (int i = threadIdx.x; i < 512; i += 512) {
        int node = nbase + i;
        offs[i] = (node < N_NODES) ? (rp[node] - base) : nedge;
    }
    __syncthreads();
    int n = bcnt[b]; if (n > BCAP) n = BCAP;
    const unsigned int* pb = packed + (size_t)b * BCAP;
    for (int i = threadIdx.x; i < n; i += 512) {
        unsigned int p = pb[i];
        int pos = atomicAdd(&offs[p & 511u], 1);
        if (pos < BCAP) elds[pos] = (int)(p >> SH);
    }
    __syncthreads();
    for (int i = threadIdx.x; i < nedge; i += 512)
        csr[base + i] = elds[i];
}

// ---------------- MFMA GEMM: in[N,K] @ W[K,64] -> out slice-major bf16 --------
// K=128: x is wire input (node-major). K=64: x is slice-major bf16 ws.
// Output: out[s][node][8] with s = col>>3.
template <int K>
__global__ __launch_bounds__(256) void k_gemm(const void* __restrict__ x,
                                              const void* __restrict__ W,
                                              const float* __restrict__ dis,
                                              unsigned short* __restrict__ out,  // slice-major
                                              const int* __restrict__ flags,
                                              int x_is_f32) {
    int Wf32 = flags[0];
    int xF32 = (x_is_f32 < 0) ? Wf32 : x_is_f32;
    __shared__ unsigned short Wt[64][K + 8];
    __shared__ unsigned short xs[32][K + 8];
    int t = threadIdx.x;
    int wave = t >> 6, lane = t & 63;
    int quad = lane >> 4, l16 = lane & 15;

    for (int id = t; id < 64 * K; id += 256) {
        int k = id >> 6, n = id & 63;
        Wt[n][k] = f2bf(loadf(W, id, Wf32));
    }
    __syncthreads();

    bf16x8 bfrag[K / 32];
#pragma unroll
    for (int c = 0; c < K / 32; ++c)
        bfrag[c] = *reinterpret_cast<bf16x8*>(&Wt[wave * 16 + l16][c * 32 + quad * 8]);

    const int ngroups = (N_NODES + 31) / 32;
    for (int g = blockIdx.x; g < ngroups; g += gridDim.x) {
        __syncthreads();
        int row0 = g * 32;
        if (K == 128) {
            // wire input, node-major
            for (int cid = t; cid < 4 * K; cid += 256) {
                int rr = cid / (K / 8), c8 = cid % (K / 8);
                int r = row0 + rr;
                u32x4 val = {0u, 0u, 0u, 0u};
                if (r < N_NODES) {
                    size_t base = (size_t)r * K + c8 * 8;
                    if (xF32) {
                        const u32x4* xp = (const u32x4*)x;
                        u32x4 q0 = xp[base / 4];
                        u32x4 q1 = xp[base / 4 + 1];
                        val.x = f2bf(__uint_as_float(q0.x)) | ((unsigned int)f2bf(__uint_as_float(q0.y)) << 16);
                        val.y = f2bf(__uint_as_float(q0.z)) | ((unsigned int)f2bf(__uint_as_float(q0.w)) << 16);
                        val.z = f2bf(__uint_as_float(q1.x)) | ((unsigned int)f2bf(__uint_as_float(q1.y)) << 16);
                        val.w = f2bf(__uint_as_float(q1.z)) | ((unsigned int)f2bf(__uint_as_float(q1.w)) << 16);
                    } else {
                        val = ((const u32x4*)x)[base / 8];
                    }
                }
                *reinterpret_cast<u32x4*>(&xs[rr][c8 * 8]) = val;
            }
        } else {
            // slice-major bf16 ws: item idx -> (sq = s*4+q slow, rr fast)
            const unsigned int* hsrc = (const unsigned int*)x;
            for (int it = 0; it < 4; ++it) {
                int idx = it * 256 + t;          // 0..1023
                int rr = idx & 31;
                int sq = idx >> 5;               // 0..31  (s = sq>>2, q = sq&3)
                int r = row0 + rr;
                unsigned int v = 0u;
                if (r < N_NODES)
                    v = hsrc[(size_t)(sq >> 2) * SLICE_U + (size_t)r * 4 + (sq & 3)];
                *reinterpret_cast<unsigned int*>(&xs[rr][sq * 2]) = v;
            }
        }
        __syncthreads();

        f32x4 acc0 = {0.f, 0.f, 0.f, 0.f};
        f32x4 acc1 = {0.f, 0.f, 0.f, 0.f};
#pragma unroll
        for (int c = 0; c < K / 32; ++c) {
            bf16x8 a0 = *reinterpret_cast<bf16x8*>(&xs[l16][c * 32 + quad * 8]);
            bf16x8 a1 = *reinterpret_cast<bf16x8*>(&xs[16 + l16][c * 32 + quad * 8]);
            acc0 = __builtin_amdgcn_mfma_f32_16x16x32_bf16(a0, bfrag[c], acc0, 0, 0, 0);
            acc1 = __builtin_amdgcn_mfma_f32_16x16x32_bf16(a1, bfrag[c], acc1, 0, 0, 0);
        }
        int col = wave * 16 + l16;
        unsigned short* outs = out + (size_t)(col >> 3) * SLICE_E + (col & 7);
#pragma unroll
        for (int reg = 0; reg < 4; ++reg) {
            int r0 = row0 + quad * 4 + reg;
            if (r0 < N_NODES) outs[(size_t)r0 * 8] = f2bf(acc0[reg] * dis[r0]);
            int r1 = row0 + 16 + quad * 4 + reg;
            if (r1 < N_NODES) outs[(size_t)r1 * 8] = f2bf(acc1[reg] * dis[r1]);
        }
    }
}

// ---------------- fused gather, XCD-sharded feature slice ---------------------
// blockIdx&7 = slice s = XCD (round-robin dispatch heuristic, perf-only).
// Per XCD the slice working set is 1.6 MB -> L2-resident. Wave = node;
// lane = nsub*4 + q: 16 neighbors in flight, q picks 4 B (2 feats) of the
// 16 B slice row. Dense per-slice writes (single-XCD line ownership).
__global__ __launch_bounds__(256) void k_gather(const int* __restrict__ rp,
                                                const int* __restrict__ csr,
                                                const float* __restrict__ dis,
                                                const unsigned short* __restrict__ xws,
                                                const void* __restrict__ b,
                                                unsigned short* __restrict__ out,
                                                int do_relu,
                                                const int* __restrict__ flags) {
    int F32 = flags[0];
    int s = blockIdx.x & 7;
    int m = blockIdx.x >> 3;
    int wave = threadIdx.x >> 6, lane = threadIdx.x & 63;
    int node = m * 4 + wave;
    if (node >= N_NODES) return;
    int q = lane & 3, nsub = lane >> 2;
    int start = rp[node], end = rp[node + 1];
    const unsigned int* xsl = (const unsigned int*)xws + (size_t)s * SLICE_U;
    float a0 = 0.f, a1 = 0.f;
    for (int j = start + nsub; j < end; j += 16) {
        int src = csr[j];
        unsigned int v = xsl[(size_t)src * 4 + q];
        a0 += bf2f(v & 0xFFFFu);
        a1 += bf2f(v >> 16);
    }
#pragma unroll
    for (int off = 32; off >= 4; off >>= 1) {
        a0 += __shfl_down(a0, off, 64);
        a1 += __shfl_down(a1, off, 64);
    }
    if (nsub == 0) {
        unsigned int sv = xsl[(size_t)node * 4 + q];
        float dn = dis[node];
        int fb = s * 8 + q * 2;
        float v0 = fmaf(a0 + bf2f(sv & 0xFFFFu), dn, loadf(b, fb + 0, F32));
        float v1 = fmaf(a1 + bf2f(sv >> 16),     dn, loadf(b, fb + 1, F32));
        if (do_relu) { v0 = fmaxf(v0, 0.f); v1 = fmaxf(v1, 0.f); }
        unsigned int o = f2bf(v0) | ((unsigned int)f2bf(v1) << 16);
        ((unsigned int*)out)[(size_t)s * SLICE_U + (size_t)node * 4 + q] = o;
    }
}

// ---------------- fused mean-pool + linear head (slice-major bf16 h) ----------
__global__ void k_pool_final(const int* __restrict__ gptr,
                             const unsigned short* __restrict__ h,
                             const void* __restrict__ Wl, const void* __restrict__ bl,
                             void* __restrict__ out, const int* __restrict__ flags) {
    int F32 = flags[0];
    int g = blockIdx.x;
    int lane = threadIdx.x;  // 64
    int s = gptr[g], e = gptr[g + 1];
    const unsigned short* hs = h + (size_t)(lane >> 3) * SLICE_E + (lane & 7);
    float acc = 0.0f;
    for (int n = s; n < e; ++n) acc += bf2f(hs[(size_t)n * 8]);
    float cnt = fmaxf((float)(e - s), 1.0f);
    float v = (acc / cnt) * loadf(Wl, lane, F32);
#pragma unroll
    for (int o = 32; o > 0; o >>= 1) v += __shfl_down(v, o, 64);
    if (lane == 0) {
        float r = v + loadf(bl, 0, F32);
        if (F32) ((float*)out)[g] = r;
        else     ((__hip_bfloat16*)out)[g] = __float2bfloat16(r);
    }
}

extern "C" void kernel_launch(void* const* d_in, const int* in_sizes, int n_in,
                              void* d_out, int out_size, void* d_ws, size_t ws_size,
                              hipStream_t stream) {
    const void* x     = d_in[0];
    const void* ei    = d_in[1];
    const void* batch = d_in[2];
    const void* W1 = d_in[3];
    const void* b1 = d_in[4];
    const void* W2 = d_in[5];
    const void* b2 = d_in[6];
    const void* W3 = d_in[7];
    const void* b3 = d_in[8];
    const void* Wl = d_in[9];
    const void* bl = d_in[10];

    // workspace layout (~41 MB)
    float* dis   = (float*)d_ws;             // 100352
    int*   cnt   = (int*)(dis + 100352);     // 100352
    int*   rp    = cnt + 100352;             // 100352 (needs 100001)
    int*   csr   = rp + 100352;              // 1600000
    int*   gcnt  = csr + 1600000;            // 1024
    int*   gptr  = gcnt + 1024;              // 1056 (needs 1025)
    int*   partN = gptr + 1056;              // 512
    int*   partG = partN + 512;              // 512 (unused)
    int*   bcnt  = partG + 512;              // 256
    int*   flags = bcnt + 256;               // 16
    unsigned int* packed = (unsigned int*)(flags + 16);    // NB*BCAP (7.8 MB)
    unsigned short* bufA = (unsigned short*)(packed + (size_t)NB * BCAP);  // slice-major xws (12.8 MB)
    unsigned short* bufB = bufA + 6400000;                 // slice-major h (12.8 MB)

    const int TB = 256;
    dim3 blk(TB);
    int gN  = (N_NODES + TB - 1) / TB;       // 391
    int gG  = 8 * ((N_NODES + 3) / 4);       // 200000 (8 slices x 25000)

    // init: detect + zero
    k_init<<<1, blk, 0, stream>>>((const unsigned int*)x, (const unsigned int*)ei,
                                  flags, gcnt, bcnt);
    // phase A partition (+ batch counts)
    k_part<<<(N_EDGES + 1023) / 1024, blk, 0, stream>>>(ei, batch, bcnt, gcnt, packed, flags);
    // hist: cnt + dis + scan partials
    k_hist<<<NBU, blk, 0, stream>>>(packed, bcnt, cnt, dis, partN);
    // middle scan: partN exclusive + rp[N], graph scan -> gptr
    k_scan_mid<<<1, 512, 0, stream>>>(partN, gN, rp, N_NODES, gcnt, gptr);
    // p3: rp
    k_scan_p3<<<gN, blk, 0, stream>>>(cnt, partN, rp, N_NODES);
    // phase B: dense csr
    k_bucketcsr<<<NBU, 512, 0, stream>>>(packed, bcnt, rp, csr);

    // ---- layer 1 ----
    k_gemm<F_IN><<<1024, blk, 0, stream>>>(x, W1, dis, bufA, flags, -1);
    k_gather<<<gG, blk, 0, stream>>>(rp, csr, dis, bufA, b1, bufB, 1, flags);
    // ---- layer 2 ----
    k_gemm<HID><<<1024, blk, 0, stream>>>(bufB, W2, dis, bufA, flags, 0);
    k_gather<<<gG, blk, 0, stream>>>(rp, csr, dis, bufA, b2, bufB, 1, flags);
    // ---- layer 3 ----
    k_gemm<HID><<<1024, blk, 0, stream>>>(bufB, W3, dis, bufA, flags, 0);
    k_gather<<<gG, blk, 0, stream>>>(rp, csr, dis, bufA, b3, bufB, 0, flags);

    // ---- pool + head ----
    k_pool_final<<<N_GRAPHS, 64, 0, stream>>>(gptr, bufB, Wl, bl, d_out, flags);
}

// Round 12
// 611.639 us; speedup vs baseline: 1.3234x; 1.3234x over previous
//
#include <hip/hip_runtime.h>
#include <hip/hip_bf16.h>

#define N_NODES 100000
#define N_EDGES 1600000
#define F_IN 128
#define HID 64
#define N_GRAPHS 1024

// fine dst-partition for CSR build: bucket = dst>>9 (512 nodes/bucket)
#define SH 9
#define NBU 196        // buckets used: ceil(100000/512)
#define NB 200         // allocated
#define BCAP 9728      // mean 8192 + 17 sigma

typedef __attribute__((ext_vector_type(8))) short bf16x8;
typedef __attribute__((ext_vector_type(4))) float f32x4;
typedef __attribute__((ext_vector_type(4))) unsigned int u32x4;

// ---------------- bf16 bit helpers --------------------------------------------
__device__ __forceinline__ unsigned short f2bf(float f) {
    __hip_bfloat16 h = __float2bfloat16(f);   // RNE
    return *reinterpret_cast<unsigned short*>(&h);
}
__device__ __forceinline__ float bf2f(unsigned int u) {
    return __uint_as_float(u << 16);
}

// ---------------- dual-path load helpers (wire dtype resolved at runtime) -----
__device__ __forceinline__ float loadf(const void* p, size_t i, int f32) {
    if (f32) return ((const float*)p)[i];
    return __bfloat162float(((const __hip_bfloat16*)p)[i]);
}
__device__ __forceinline__ int loadi(const void* p, size_t i, int i64) {
    if (i64) return (int)((const long long*)p)[i];
    return ((const int*)p)[i];
}

// ---------------- init: wire detect + zero small counters ---------------------
__global__ void k_init(const unsigned int* __restrict__ xw_,
                       const unsigned int* __restrict__ ei_,
                       int* __restrict__ flags,
                       int* __restrict__ gcnt, int* __restrict__ bcnt) {
    __shared__ int cnt_f, cnt_i;
    int t = threadIdx.x;
    if (t == 0) { cnt_f = 0; cnt_i = 0; }
    __syncthreads();
    unsigned int w = xw_[t];
    unsigned int e = (w >> 7) & 0xFFu;
    if (e >= 100u && e <= 140u) atomicAdd(&cnt_f, 1);
    unsigned int iw = ei_[2 * t + 1];
    if (iw == 0u) atomicAdd(&cnt_i, 1);
    for (int i = t; i < N_GRAPHS; i += 256) gcnt[i] = 0;
    for (int i = t; i < NB; i += 256) bcnt[i] = 0;
    __syncthreads();
    if (t == 0) {
        flags[0] = (cnt_f < 180) ? 1 : 0;   // 1 => fp32 wire
        flags[1] = (cnt_i >= 128) ? 1 : 0;  // 1 => int64 wire
    }
}

// ---------------- phase A: partition by dst>>9 (+ batch count + pooled zero) --
// packed entry: (src << 9) | (dst & 511). PLAIN stores (NT stores caused 77 MB
// write-amp in R10 -- partial lines bypass L2 merging).
__global__ __launch_bounds__(256) void k_part(const void* __restrict__ ei,
                                              const void* __restrict__ batch,
                                              int* __restrict__ bcnt,
                                              int* __restrict__ gcnt,
                                              unsigned int* __restrict__ packed,
                                              float* __restrict__ pooled,
                                              const int* __restrict__ flags) {
    int I64 = flags[1];
    __shared__ int hist[NB];
    __shared__ int base[NB];
    int t = threadIdx.x;
    if (t < NB) hist[t] = 0;
    {
        int n = blockIdx.x * 256 + t;
        if (n < N_NODES) atomicAdd(&gcnt[loadi(batch, n, I64)], 1);
        if (blockIdx.x < 256) pooled[blockIdx.x * 256 + t] = 0.0f;  // 64K floats
    }
    __syncthreads();
    int e0 = blockIdx.x * 1024;
    int b[4], r[4];
    unsigned int pk[4];
    for (int it = 0; it < 4; ++it) {
        int e = e0 + it * 256 + t;
        b[it] = -1;
        if (e < N_EDGES) {
            int s = loadi(ei, e, I64);
            int d = loadi(ei, (size_t)N_EDGES + e, I64);
            b[it] = d >> SH;
            pk[it] = ((unsigned int)s << SH) | (unsigned int)(d & 511);
            r[it] = atomicAdd(&hist[b[it]], 1);   // LDS rank
        }
    }
    __syncthreads();
    if (t < NB) base[t] = hist[t] ? atomicAdd(&bcnt[t], hist[t]) : 0;
    __syncthreads();
    for (int it = 0; it < 4; ++it) {
        if (b[it] >= 0) {
            int pos = base[b[it]] + r[it];
            if (pos < BCAP) packed[(size_t)b[it] * BCAP + pos] = pk[it];
        }
    }
}

// ---------------- hist: in-degree + dis + scan partials (fused) ---------------
__global__ __launch_bounds__(256) void k_hist(const unsigned int* __restrict__ packed,
                                              const int* __restrict__ bcnt,
                                              int* __restrict__ cnt,
                                              float* __restrict__ dis,
                                              int* __restrict__ partN) {
    __shared__ int hist[512];
    int b = blockIdx.x;
    int t = threadIdx.x;
    int n = bcnt[b];
    if (n > BCAP) n = BCAP;
    for (int i = t; i < 512; i += 256) hist[i] = 0;
    __syncthreads();
    const unsigned int* pb = packed + (size_t)b * BCAP;
    for (int i = t; i < n; i += 256)
        atomicAdd(&hist[pb[i] & 511u], 1);
    __syncthreads();
    int nbase = b << SH;
    for (int i = t; i < 512; i += 256) {
        int node = nbase + i;
        if (node < N_NODES) {
            int c = hist[i];
            cnt[node] = c;
            dis[node] = rsqrtf((float)c + 1.0f);
        }
    }
    __syncthreads();
    for (int off = 128; off > 0; off >>= 1) {
        if (t < off) { hist[t] += hist[t + off]; hist[256 + t] += hist[256 + t + off]; }
        __syncthreads();
    }
    if (t == 0) {
        partN[2 * b] = hist[0];
        if (2 * b + 1 < 391) partN[2 * b + 1] = hist[256];
    }
}

// ---------------- middle scan: partN (391) exclusive + rp[N] ------------------
__global__ void k_scan_mid(int* __restrict__ partial, int nb,
                           int* __restrict__ rp, int n) {
    __shared__ int s[512];
    int t = threadIdx.x;
    int v = (t < nb) ? partial[t] : 0;
    s[t] = v;
    __syncthreads();
    for (int off = 1; off < 512; off <<= 1) {
        int x = (t >= off) ? s[t - off] : 0;
        __syncthreads();
        s[t] += x;
        __syncthreads();
    }
    if (t < nb) partial[t] = s[t] - v;   // exclusive
    if (t == 511) rp[n] = s[511];        // grand total
}

// ---------------- scan p3: per-256-chunk local scan + offset -> rp ------------
__global__ void k_scan_p3(const int* __restrict__ in, const int* __restrict__ partial,
                          int* __restrict__ out, int n) {
    __shared__ int s[256];
    int t = threadIdx.x;
    int i = blockIdx.x * 256 + t;
    int v = (i < n) ? in[i] : 0;
    s[t] = v;
    __syncthreads();
    for (int off = 1; off < 256; off <<= 1) {
        int x = (t >= off) ? s[t - off] : 0;
        __syncthreads();
        s[t] += x;
        __syncthreads();
    }
    if (i < n) out[i] = partial[blockIdx.x] + s[t] - v;
}

// ---------------- phase B: LDS counting-sort, dense csr writes ----------------
__global__ __launch_bounds__(512) void k_bucketcsr(const unsigned int* __restrict__ packed,
                                                   const int* __restrict__ bcnt,
                                                   const int* __restrict__ rp,
                                                   int* __restrict__ csr) {
    __shared__ int offs[512];
    __shared__ int elds[BCAP];    // 38 KB
    int b = blockIdx.x;
    int nbase = b << SH;
    int base = rp[nbase];
    int lim = nbase + 512; if (lim > N_NODES) lim = N_NODES;
    int nedge = rp[lim] - base;
    if (nedge > BCAP) nedge = BCAP;
    for (int i = threadIdx.x; i < 512; i += 512) {
        int node = nbase + i;
        offs[i] = (node < N_NODES) ? (rp[node] - base) : nedge;
    }
    __syncthreads();
    int n = bcnt[b]; if (n > BCAP) n = BCAP;
    const unsigned int* pb = packed + (size_t)b * BCAP;
    for (int i = threadIdx.x; i < n; i += 512) {
        unsigned int p = pb[i];
        int pos = atomicAdd(&offs[p & 511u], 1);
        if (pos < BCAP) elds[pos] = (int)(p >> SH);
    }
    __syncthreads();
    for (int i = threadIdx.x; i < nedge; i += 512)
        csr[base + i] = elds[i];
}

// ---------------- MFMA GEMM: in[N,K] @ W[K,64] -> out[N,64] bf16, x dis[row] --
template <int K>
__global__ __launch_bounds__(256) void k_gemm(const void* __restrict__ x,
                                              const void* __restrict__ W,
                                              const float* __restrict__ dis,
                                              unsigned short* __restrict__ out,  // bf16 bits
                                              const int* __restrict__ flags,
                                              int x_is_f32) {
    int Wf32 = flags[0];
    int xF32 = (x_is_f32 < 0) ? Wf32 : x_is_f32;
    __shared__ unsigned short Wt[64][K + 8];
    __shared__ unsigned short xs[32][K + 8];
    int t = threadIdx.x;
    int wave = t >> 6, lane = t & 63;
    int quad = lane >> 4, l16 = lane & 15;

    for (int id = t; id < 64 * K; id += 256) {
        int k = id >> 6, n = id & 63;
        Wt[n][k] = f2bf(loadf(W, id, Wf32));
    }
    __syncthreads();

    bf16x8 bfrag[K / 32];
#pragma unroll
    for (int c = 0; c < K / 32; ++c)
        bfrag[c] = *reinterpret_cast<bf16x8*>(&Wt[wave * 16 + l16][c * 32 + quad * 8]);

    const int ngroups = (N_NODES + 31) / 32;
    for (int g = blockIdx.x; g < ngroups; g += gridDim.x) {
        __syncthreads();
        int row0 = g * 32;
        for (int cid = t; cid < 4 * K; cid += 256) {
            int rr = cid / (K / 8), c8 = cid % (K / 8);
            int r = row0 + rr;
            u32x4 val = {0u, 0u, 0u, 0u};
            if (r < N_NODES) {
                size_t base = (size_t)r * K + c8 * 8;
                if (xF32) {
                    const u32x4* xp = (const u32x4*)x;
                    u32x4 q0 = xp[base / 4];
                    u32x4 q1 = xp[base / 4 + 1];
                    val.x = f2bf(__uint_as_float(q0.x)) | ((unsigned int)f2bf(__uint_as_float(q0.y)) << 16);
                    val.y = f2bf(__uint_as_float(q0.z)) | ((unsigned int)f2bf(__uint_as_float(q0.w)) << 16);
                    val.z = f2bf(__uint_as_float(q1.x)) | ((unsigned int)f2bf(__uint_as_float(q1.y)) << 16);
                    val.w = f2bf(__uint_as_float(q1.z)) | ((unsigned int)f2bf(__uint_as_float(q1.w)) << 16);
                } else {
                    val = ((const u32x4*)x)[base / 8];
                }
            }
            *reinterpret_cast<u32x4*>(&xs[rr][c8 * 8]) = val;
        }
        __syncthreads();

        f32x4 acc0 = {0.f, 0.f, 0.f, 0.f};
        f32x4 acc1 = {0.f, 0.f, 0.f, 0.f};
#pragma unroll
        for (int c = 0; c < K / 32; ++c) {
            bf16x8 a0 = *reinterpret_cast<bf16x8*>(&xs[l16][c * 32 + quad * 8]);
            bf16x8 a1 = *reinterpret_cast<bf16x8*>(&xs[16 + l16][c * 32 + quad * 8]);
            acc0 = __builtin_amdgcn_mfma_f32_16x16x32_bf16(a0, bfrag[c], acc0, 0, 0, 0);
            acc1 = __builtin_amdgcn_mfma_f32_16x16x32_bf16(a1, bfrag[c], acc1, 0, 0, 0);
        }
        int col = wave * 16 + l16;
#pragma unroll
        for (int reg = 0; reg < 4; ++reg) {
            int r0 = row0 + quad * 4 + reg;
            if (r0 < N_NODES) out[(size_t)r0 * 64 + col] = f2bf(acc0[reg] * dis[r0]);
            int r1 = row0 + 16 + quad * 4 + reg;
            if (r1 < N_NODES) out[(size_t)r1 * 64 + col] = f2bf(acc1[reg] * dis[r1]);
        }
    }
}

// ---------------- fused gather + self-loop + bias + relu (+ optional pool) ----
// Node-major bf16 rows (128 B). Wave = node; lane = nsub*8 + f8: 8 neighbors
// in flight, each lane loads uint4 (8 bf16). csr index prefetched one trip
// ahead. do_pool: last layer accumulates straight into pooled[g][f] (fp32
// atomics, 256 KB L2-resident) and skips the h write entirely.
__global__ __launch_bounds__(256) void k_gather(const int* __restrict__ rp,
                                                const int* __restrict__ csr,
                                                const float* __restrict__ dis,
                                                const unsigned short* __restrict__ xws,
                                                const void* __restrict__ b,
                                                unsigned short* __restrict__ out,
                                                const void* __restrict__ batch,
                                                float* __restrict__ pooled,
                                                int do_relu, int do_pool,
                                                const int* __restrict__ flags) {
    int F32 = flags[0];
    int wave = threadIdx.x >> 6, lane = threadIdx.x & 63;
    int node = blockIdx.x * 4 + wave;
    if (node >= N_NODES) return;
    int f8 = lane & 7, nsub = lane >> 3;
    int start = rp[node], end = rp[node + 1];
    const uint4* x8 = (const uint4*)xws;   // row = 8 uint4 (128 B)
    float a0 = 0, a1 = 0, a2 = 0, a3 = 0, a4 = 0, a5 = 0, a6 = 0, a7 = 0;
    int j = start + nsub;
    if (j < end) {
        int s = csr[j];
        for (;;) {
            int jn = j + 8;
            int sn = (jn < end) ? csr[jn] : 0;     // prefetch next index
            uint4 v = x8[(size_t)s * 8 + f8];
            a0 += bf2f(v.x & 0xFFFFu); a1 += bf2f(v.x >> 16);
            a2 += bf2f(v.y & 0xFFFFu); a3 += bf2f(v.y >> 16);
            a4 += bf2f(v.z & 0xFFFFu); a5 += bf2f(v.z >> 16);
            a6 += bf2f(v.w & 0xFFFFu); a7 += bf2f(v.w >> 16);
            if (jn >= end) break;
            j = jn; s = sn;
        }
    }
#pragma unroll
    for (int off = 32; off >= 8; off >>= 1) {
        a0 += __shfl_down(a0, off, 64); a1 += __shfl_down(a1, off, 64);
        a2 += __shfl_down(a2, off, 64); a3 += __shfl_down(a3, off, 64);
        a4 += __shfl_down(a4, off, 64); a5 += __shfl_down(a5, off, 64);
        a6 += __shfl_down(a6, off, 64); a7 += __shfl_down(a7, off, 64);
    }
    if (nsub == 0) {
        uint4 sv = x8[(size_t)node * 8 + f8];
        float dn = dis[node];
        float v0 = fmaf(a0 + bf2f(sv.x & 0xFFFFu), dn, loadf(b, 8 * f8 + 0, F32));
        float v1 = fmaf(a1 + bf2f(sv.x >> 16),     dn, loadf(b, 8 * f8 + 1, F32));
        float v2 = fmaf(a2 + bf2f(sv.y & 0xFFFFu), dn, loadf(b, 8 * f8 + 2, F32));
        float v3 = fmaf(a3 + bf2f(sv.y >> 16),     dn, loadf(b, 8 * f8 + 3, F32));
        float v4 = fmaf(a4 + bf2f(sv.z & 0xFFFFu), dn, loadf(b, 8 * f8 + 4, F32));
        float v5 = fmaf(a5 + bf2f(sv.z >> 16),     dn, loadf(b, 8 * f8 + 5, F32));
        float v6 = fmaf(a6 + bf2f(sv.w & 0xFFFFu), dn, loadf(b, 8 * f8 + 6, F32));
        float v7 = fmaf(a7 + bf2f(sv.w >> 16),     dn, loadf(b, 8 * f8 + 7, F32));
        if (do_relu) {
            v0 = fmaxf(v0, 0.f); v1 = fmaxf(v1, 0.f); v2 = fmaxf(v2, 0.f); v3 = fmaxf(v3, 0.f);
            v4 = fmaxf(v4, 0.f); v5 = fmaxf(v5, 0.f); v6 = fmaxf(v6, 0.f); v7 = fmaxf(v7, 0.f);
        }
        if (do_pool) {
            int g = loadi(batch, node, flags[1]);
            float* pg = &pooled[(size_t)g * 64 + 8 * f8];
            atomicAdd(&pg[0], v0); atomicAdd(&pg[1], v1);
            atomicAdd(&pg[2], v2); atomicAdd(&pg[3], v3);
            atomicAdd(&pg[4], v4); atomicAdd(&pg[5], v5);
            atomicAdd(&pg[6], v6); atomicAdd(&pg[7], v7);
        } else {
            uint4 o;
            o.x = f2bf(v0) | ((unsigned int)f2bf(v1) << 16);
            o.y = f2bf(v2) | ((unsigned int)f2bf(v3) << 16);
            o.z = f2bf(v4) | ((unsigned int)f2bf(v5) << 16);
            o.w = f2bf(v6) | ((unsigned int)f2bf(v7) << 16);
            ((uint4*)out)[(size_t)node * 8 + f8] = o;
        }
    }
}

// ---------------- head: out[g] = (pooled[g]/cnt) . Wl + bl --------------------
__global__ void k_head(const float* __restrict__ pooled, const int* __restrict__ gcnt,
                       const void* __restrict__ Wl, const void* __restrict__ bl,
                       void* __restrict__ out, const int* __restrict__ flags) {
    int F32 = flags[0];
    int g = blockIdx.x;
    int lane = threadIdx.x;  // 64
    float cnt = fmaxf((float)gcnt[g], 1.0f);
    float v = (pooled[(size_t)g * 64 + lane] / cnt) * loadf(Wl, lane, F32);
#pragma unroll
    for (int o = 32; o > 0; o >>= 1) v += __shfl_down(v, o, 64);
    if (lane == 0) {
        float r = v + loadf(bl, 0, F32);
        if (F32) ((float*)out)[g] = r;
        else     ((__hip_bfloat16*)out)[g] = __float2bfloat16(r);
    }
}

extern "C" void kernel_launch(void* const* d_in, const int* in_sizes, int n_in,
                              void* d_out, int out_size, void* d_ws, size_t ws_size,
                              hipStream_t stream) {
    const void* x     = d_in[0];
    const void* ei    = d_in[1];
    const void* batch = d_in[2];
    const void* W1 = d_in[3];
    const void* b1 = d_in[4];
    const void* W2 = d_in[5];
    const void* b2 = d_in[6];
    const void* W3 = d_in[7];
    const void* b3 = d_in[8];
    const void* Wl = d_in[9];
    const void* bl = d_in[10];

    // workspace layout (~41.3 MB)
    float* dis    = (float*)d_ws;             // 100352
    int*   cnt    = (int*)(dis + 100352);     // 100352
    int*   rp     = cnt + 100352;             // 100352 (needs 100001)
    int*   csr    = rp + 100352;              // 1600000
    int*   gcnt   = csr + 1600000;            // 1024
    int*   partN  = gcnt + 1024;              // 512
    int*   bcnt   = partN + 512;              // 256
    int*   flags  = bcnt + 256;               // 16
    float* pooled = (float*)(flags + 16);     // 65536 (256 KB)
    unsigned int* packed = (unsigned int*)(pooled + 65536);  // NB*BCAP (7.8 MB)
    unsigned short* bufA = (unsigned short*)(packed + (size_t)NB * BCAP);  // bf16 xws (12.8 MB)
    unsigned short* bufB = bufA + 6400000;                  // bf16 h (12.8 MB)

    const int TB = 256;
    dim3 blk(TB);
    int gN  = (N_NODES + TB - 1) / TB;       // 391
    int gG4 = (N_NODES + 3) / 4;             // 25000 (gather blocks)

    // init: detect + zero small counters
    k_init<<<1, blk, 0, stream>>>((const unsigned int*)x, (const unsigned int*)ei,
                                  flags, gcnt, bcnt);
    // phase A partition (+ batch counts + pooled zero)
    k_part<<<(N_EDGES + 1023) / 1024, blk, 0, stream>>>(ei, batch, bcnt, gcnt, packed,
                                                        pooled, flags);
    // hist: cnt + dis + scan partials
    k_hist<<<NBU, blk, 0, stream>>>(packed, bcnt, cnt, dis, partN);
    // middle scan: partN exclusive + rp[N]
    k_scan_mid<<<1, 512, 0, stream>>>(partN, gN, rp, N_NODES);
    // p3: rp
    k_scan_p3<<<gN, blk, 0, stream>>>(cnt, partN, rp, N_NODES);
    // phase B: dense csr
    k_bucketcsr<<<NBU, 512, 0, stream>>>(packed, bcnt, rp, csr);

    // ---- layer 1 ----
    k_gemm<F_IN><<<1024, blk, 0, stream>>>(x, W1, dis, bufA, flags, -1);
    k_gather<<<gG4, blk, 0, stream>>>(rp, csr, dis, bufA, b1, bufB, batch, pooled, 1, 0, flags);
    // ---- layer 2 ----
    k_gemm<HID><<<1024, blk, 0, stream>>>(bufB, W2, dis, bufA, flags, 0);
    k_gather<<<gG4, blk, 0, stream>>>(rp, csr, dis, bufA, b2, bufB, batch, pooled, 1, 0, flags);
    // ---- layer 3 (pool fused: writes pooled, skips h3) ----
    k_gemm<HID><<<1024, blk, 0, stream>>>(bufB, W3, dis, bufA, flags, 0);
    k_gather<<<gG4, blk, 0, stream>>>(rp, csr, dis, bufA, b3, bufB, batch, pooled, 0, 1, flags);

    // ---- head ----
    k_head<<<N_GRAPHS, 64, 0, stream>>>(pooled, gcnt, Wl, bl, d_out, flags);
}

// Round 13
// 429.412 us; speedup vs baseline: 1.8850x; 1.4244x over previous
//
#include <hip/hip_runtime.h>
#include <hip/hip_bf16.h>

#define N_NODES 100000
#define N_EDGES 1600000
#define F_IN 128
#define HID 64
#define N_GRAPHS 1024

// fine dst-partition for CSR build: bucket = dst>>9 (512 nodes/bucket)
#define SH 9
#define NBU 196        // buckets used: ceil(100000/512)
#define NB 200         // allocated
#define BCAP 9728      // mean 8192 + 17 sigma

typedef __attribute__((ext_vector_type(8))) short bf16x8;
typedef __attribute__((ext_vector_type(4))) float f32x4;
typedef __attribute__((ext_vector_type(4))) unsigned int u32x4;

// ---------------- bf16 bit helpers --------------------------------------------
__device__ __forceinline__ unsigned short f2bf(float f) {
    __hip_bfloat16 h = __float2bfloat16(f);   // RNE
    return *reinterpret_cast<unsigned short*>(&h);
}
__device__ __forceinline__ float bf2f(unsigned int u) {
    return __uint_as_float(u << 16);
}

// ---------------- dual-path load helpers (wire dtype resolved at runtime) -----
__device__ __forceinline__ float loadf(const void* p, size_t i, int f32) {
    if (f32) return ((const float*)p)[i];
    return __bfloat162float(((const __hip_bfloat16*)p)[i]);
}
__device__ __forceinline__ int loadi(const void* p, size_t i, int i64) {
    if (i64) return (int)((const long long*)p)[i];
    return ((const int*)p)[i];
}

// ---------------- init: wire detect + zero small counters ---------------------
__global__ void k_init(const unsigned int* __restrict__ xw_,
                       const unsigned int* __restrict__ ei_,
                       int* __restrict__ flags,
                       int* __restrict__ gcnt, int* __restrict__ bcnt) {
    __shared__ int cnt_f, cnt_i;
    int t = threadIdx.x;
    if (t == 0) { cnt_f = 0; cnt_i = 0; }
    __syncthreads();
    unsigned int w = xw_[t];
    unsigned int e = (w >> 7) & 0xFFu;
    if (e >= 100u && e <= 140u) atomicAdd(&cnt_f, 1);
    unsigned int iw = ei_[2 * t + 1];
    if (iw == 0u) atomicAdd(&cnt_i, 1);
    for (int i = t; i < N_GRAPHS; i += 256) gcnt[i] = 0;
    for (int i = t; i < NB; i += 256) bcnt[i] = 0;
    __syncthreads();
    if (t == 0) {
        flags[0] = (cnt_f < 180) ? 1 : 0;   // 1 => fp32 wire
        flags[1] = (cnt_i >= 128) ? 1 : 0;  // 1 => int64 wire
    }
}

// ---------------- phase A: partition by dst>>9 (+ fused batch count) ----------
// packed entry: (src << 9) | (dst & 511). PLAIN stores (NT stores caused 77 MB
// write-amp in R10 -- partial lines bypass L2 merging).
__global__ __launch_bounds__(256) void k_part(const void* __restrict__ ei,
                                              const void* __restrict__ batch,
                                              int* __restrict__ bcnt,
                                              int* __restrict__ gcnt,
                                              unsigned int* __restrict__ packed,
                                              const int* __restrict__ flags) {
    int I64 = flags[1];
    __shared__ int hist[NB];
    __shared__ int base[NB];
    int t = threadIdx.x;
    if (t < NB) hist[t] = 0;
    {
        int n = blockIdx.x * 256 + t;
        if (n < N_NODES) atomicAdd(&gcnt[loadi(batch, n, I64)], 1);
    }
    __syncthreads();
    int e0 = blockIdx.x * 1024;
    int b[4], r[4];
    unsigned int pk[4];
    for (int it = 0; it < 4; ++it) {
        int e = e0 + it * 256 + t;
        b[it] = -1;
        if (e < N_EDGES) {
            int s = loadi(ei, e, I64);
            int d = loadi(ei, (size_t)N_EDGES + e, I64);
            b[it] = d >> SH;
            pk[it] = ((unsigned int)s << SH) | (unsigned int)(d & 511);
            r[it] = atomicAdd(&hist[b[it]], 1);   // LDS rank
        }
    }
    __syncthreads();
    if (t < NB) base[t] = hist[t] ? atomicAdd(&bcnt[t], hist[t]) : 0;
    __syncthreads();
    for (int it = 0; it < 4; ++it) {
        if (b[it] >= 0) {
            int pos = base[b[it]] + r[it];
            if (pos < BCAP) packed[(size_t)b[it] * BCAP + pos] = pk[it];
        }
    }
}

// ---------------- hist: in-degree + dis + scan partials (fused) ---------------
__global__ __launch_bounds__(256) void k_hist(const unsigned int* __restrict__ packed,
                                              const int* __restrict__ bcnt,
                                              int* __restrict__ cnt,
                                              float* __restrict__ dis,
                                              int* __restrict__ partN) {
    __shared__ int hist[512];
    int b = blockIdx.x;
    int t = threadIdx.x;
    int n = bcnt[b];
    if (n > BCAP) n = BCAP;
    for (int i = t; i < 512; i += 256) hist[i] = 0;
    __syncthreads();
    const unsigned int* pb = packed + (size_t)b * BCAP;
    for (int i = t; i < n; i += 256)
        atomicAdd(&hist[pb[i] & 511u], 1);
    __syncthreads();
    int nbase = b << SH;
    for (int i = t; i < 512; i += 256) {
        int node = nbase + i;
        if (node < N_NODES) {
            int c = hist[i];
            cnt[node] = c;
            dis[node] = rsqrtf((float)c + 1.0f);
        }
    }
    __syncthreads();
    for (int off = 128; off > 0; off >>= 1) {
        if (t < off) { hist[t] += hist[t + off]; hist[256 + t] += hist[256 + t + off]; }
        __syncthreads();
    }
    if (t == 0) {
        partN[2 * b] = hist[0];
        if (2 * b + 1 < 391) partN[2 * b + 1] = hist[256];
    }
}

// ---------------- middle scan: partN (391) + graph scan (1024), one block -----
__global__ void k_scan_mid(int* __restrict__ partial, int nb,
                           int* __restrict__ rp, int n,
                           const int* __restrict__ gcnt, int* __restrict__ gptr) {
    __shared__ int s[512];
    int t = threadIdx.x;
    int v = (t < nb) ? partial[t] : 0;
    s[t] = v;
    __syncthreads();
    for (int off = 1; off < 512; off <<= 1) {
        int x = (t >= off) ? s[t - off] : 0;
        __syncthreads();
        s[t] += x;
        __syncthreads();
    }
    if (t < nb) partial[t] = s[t] - v;   // exclusive
    if (t == 511) rp[n] = s[511];        // grand total
    __syncthreads();
    // graph scan: 1024 elems, 2 per thread
    int a = gcnt[2 * t], bq = gcnt[2 * t + 1];
    int ps = a + bq;
    s[t] = ps;
    __syncthreads();
    for (int off = 1; off < 512; off <<= 1) {
        int x = (t >= off) ? s[t - off] : 0;
        __syncthreads();
        s[t] += x;
        __syncthreads();
    }
    int excl = s[t] - ps;
    gptr[2 * t] = excl;
    gptr[2 * t + 1] = excl + a;
    if (t == 511) gptr[1024] = s[511];
}

// ---------------- scan p3: per-256-chunk local scan + offset -> rp ------------
__global__ void k_scan_p3(const int* __restrict__ in, const int* __restrict__ partial,
                          int* __restrict__ out, int n) {
    __shared__ int s[256];
    int t = threadIdx.x;
    int i = blockIdx.x * 256 + t;
    int v = (i < n) ? in[i] : 0;
    s[t] = v;
    __syncthreads();
    for (int off = 1; off < 256; off <<= 1) {
        int x = (t >= off) ? s[t - off] : 0;
        __syncthreads();
        s[t] += x;
        __syncthreads();
    }
    if (i < n) out[i] = partial[blockIdx.x] + s[t] - v;
}

// ---------------- phase B: LDS counting-sort, dense csr writes ----------------
__global__ __launch_bounds__(512) void k_bucketcsr(const unsigned int* __restrict__ packed,
                                                   const int* __restrict__ bcnt,
                                                   const int* __restrict__ rp,
                                                   int* __restrict__ csr) {
    __shared__ int offs[512];
    __shared__ int elds[BCAP];    // 38 KB
    int b = blockIdx.x;
    int nbase = b << SH;
    int base = rp[nbase];
    int lim = nbase + 512; if (lim > N_NODES) lim = N_NODES;
    int nedge = rp[lim] - base;
    if (nedge > BCAP) nedge = BCAP;
    for (int i = threadIdx.x; i < 512; i += 512) {
        int node = nbase + i;
        offs[i] = (node < N_NODES) ? (rp[node] - base) : nedge;
    }
    __syncthreads();
    int n = bcnt[b]; if (n > BCAP) n = BCAP;
    const unsigned int* pb = packed + (size_t)b * BCAP;
    for (int i = threadIdx.x; i < n; i += 512) {
        unsigned int p = pb[i];
        int pos = atomicAdd(&offs[p & 511u], 1);
        if (pos < BCAP) elds[pos] = (int)(p >> SH);
    }
    __syncthreads();
    for (int i = threadIdx.x; i < nedge; i += 512)
        csr[base + i] = elds[i];
}

// ---------------- MFMA GEMM: in[N,K] @ W[K,64] -> out[N,64] bf16, x dis[row] --
template <int K>
__global__ __launch_bounds__(256) void k_gemm(const void* __restrict__ x,
                                              const void* __restrict__ W,
                                              const float* __restrict__ dis,
                                              unsigned short* __restrict__ out,  // bf16 bits
                                              const int* __restrict__ flags,
                                              int x_is_f32) {
    int Wf32 = flags[0];
    int xF32 = (x_is_f32 < 0) ? Wf32 : x_is_f32;
    __shared__ unsigned short Wt[64][K + 8];
    __shared__ unsigned short xs[32][K + 8];
    int t = threadIdx.x;
    int wave = t >> 6, lane = t & 63;
    int quad = lane >> 4, l16 = lane & 15;

    for (int id = t; id < 64 * K; id += 256) {
        int k = id >> 6, n = id & 63;
        Wt[n][k] = f2bf(loadf(W, id, Wf32));
    }
    __syncthreads();

    bf16x8 bfrag[K / 32];
#pragma unroll
    for (int c = 0; c < K / 32; ++c)
        bfrag[c] = *reinterpret_cast<bf16x8*>(&Wt[wave * 16 + l16][c * 32 + quad * 8]);

    const int ngroups = (N_NODES + 31) / 32;
    for (int g = blockIdx.x; g < ngroups; g += gridDim.x) {
        __syncthreads();
        int row0 = g * 32;
        for (int cid = t; cid < 4 * K; cid += 256) {
            int rr = cid / (K / 8), c8 = cid % (K / 8);
            int r = row0 + rr;
            u32x4 val = {0u, 0u, 0u, 0u};
            if (r < N_NODES) {
                size_t base = (size_t)r * K + c8 * 8;
                if (xF32) {
                    const u32x4* xp = (const u32x4*)x;
                    u32x4 q0 = xp[base / 4];
                    u32x4 q1 = xp[base / 4 + 1];
                    val.x = f2bf(__uint_as_float(q0.x)) | ((unsigned int)f2bf(__uint_as_float(q0.y)) << 16);
                    val.y = f2bf(__uint_as_float(q0.z)) | ((unsigned int)f2bf(__uint_as_float(q0.w)) << 16);
                    val.z = f2bf(__uint_as_float(q1.x)) | ((unsigned int)f2bf(__uint_as_float(q1.y)) << 16);
                    val.w = f2bf(__uint_as_float(q1.z)) | ((unsigned int)f2bf(__uint_as_float(q1.w)) << 16);
                } else {
                    val = ((const u32x4*)x)[base / 8];
                }
            }
            *reinterpret_cast<u32x4*>(&xs[rr][c8 * 8]) = val;
        }
        __syncthreads();

        f32x4 acc0 = {0.f, 0.f, 0.f, 0.f};
        f32x4 acc1 = {0.f, 0.f, 0.f, 0.f};
#pragma unroll
        for (int c = 0; c < K / 32; ++c) {
            bf16x8 a0 = *reinterpret_cast<bf16x8*>(&xs[l16][c * 32 + quad * 8]);
            bf16x8 a1 = *reinterpret_cast<bf16x8*>(&xs[16 + l16][c * 32 + quad * 8]);
            acc0 = __builtin_amdgcn_mfma_f32_16x16x32_bf16(a0, bfrag[c], acc0, 0, 0, 0);
            acc1 = __builtin_amdgcn_mfma_f32_16x16x32_bf16(a1, bfrag[c], acc1, 0, 0, 0);
        }
        int col = wave * 16 + l16;
#pragma unroll
        for (int reg = 0; reg < 4; ++reg) {
            int r0 = row0 + quad * 4 + reg;
            if (r0 < N_NODES) out[(size_t)r0 * 64 + col] = f2bf(acc0[reg] * dis[r0]);
            int r1 = row0 + 16 + quad * 4 + reg;
            if (r1 < N_NODES) out[(size_t)r1 * 64 + col] = f2bf(acc1[reg] * dis[r1]);
        }
    }
}

// ---------------- fused gather + self-loop + bias + relu (bf16 in/out) --------
// Node-major bf16 rows (128 B). Wave = node; lane = nsub*8 + f8: 8 neighbors
// in flight, each lane loads uint4 (8 bf16). csr index prefetched one trip
// ahead. (Pool fusion removed: R12 showed 6.4M atomics onto pooled = 204.8 MB
// RMW traffic, 280 us. Dense h write + separate pool kernel is 4x cheaper.)
__global__ __launch_bounds__(256) void k_gather(const int* __restrict__ rp,
                                                const int* __restrict__ csr,
                                                const float* __restrict__ dis,
                                                const unsigned short* __restrict__ xws,
                                                const void* __restrict__ b,
                                                unsigned short* __restrict__ out,
                                                int do_relu,
                                                const int* __restrict__ flags) {
    int F32 = flags[0];
    int wave = threadIdx.x >> 6, lane = threadIdx.x & 63;
    int node = blockIdx.x * 4 + wave;
    if (node >= N_NODES) return;
    int f8 = lane & 7, nsub = lane >> 3;
    int start = rp[node], end = rp[node + 1];
    const uint4* x8 = (const uint4*)xws;   // row = 8 uint4 (128 B)
    float a0 = 0, a1 = 0, a2 = 0, a3 = 0, a4 = 0, a5 = 0, a6 = 0, a7 = 0;
    int j = start + nsub;
    if (j < end) {
        int s = csr[j];
        for (;;) {
            int jn = j + 8;
            int sn = (jn < end) ? csr[jn] : 0;     // prefetch next index
            uint4 v = x8[(size_t)s * 8 + f8];
            a0 += bf2f(v.x & 0xFFFFu); a1 += bf2f(v.x >> 16);
            a2 += bf2f(v.y & 0xFFFFu); a3 += bf2f(v.y >> 16);
            a4 += bf2f(v.z & 0xFFFFu); a5 += bf2f(v.z >> 16);
            a6 += bf2f(v.w & 0xFFFFu); a7 += bf2f(v.w >> 16);
            if (jn >= end) break;
            j = jn; s = sn;
        }
    }
#pragma unroll
    for (int off = 32; off >= 8; off >>= 1) {
        a0 += __shfl_down(a0, off, 64); a1 += __shfl_down(a1, off, 64);
        a2 += __shfl_down(a2, off, 64); a3 += __shfl_down(a3, off, 64);
        a4 += __shfl_down(a4, off, 64); a5 += __shfl_down(a5, off, 64);
        a6 += __shfl_down(a6, off, 64); a7 += __shfl_down(a7, off, 64);
    }
    if (nsub == 0) {
        uint4 sv = x8[(size_t)node * 8 + f8];
        float dn = dis[node];
        float v0 = fmaf(a0 + bf2f(sv.x & 0xFFFFu), dn, loadf(b, 8 * f8 + 0, F32));
        float v1 = fmaf(a1 + bf2f(sv.x >> 16),     dn, loadf(b, 8 * f8 + 1, F32));
        float v2 = fmaf(a2 + bf2f(sv.y & 0xFFFFu), dn, loadf(b, 8 * f8 + 2, F32));
        float v3 = fmaf(a3 + bf2f(sv.y >> 16),     dn, loadf(b, 8 * f8 + 3, F32));
        float v4 = fmaf(a4 + bf2f(sv.z & 0xFFFFu), dn, loadf(b, 8 * f8 + 4, F32));
        float v5 = fmaf(a5 + bf2f(sv.z >> 16),     dn, loadf(b, 8 * f8 + 5, F32));
        float v6 = fmaf(a6 + bf2f(sv.w & 0xFFFFu), dn, loadf(b, 8 * f8 + 6, F32));
        float v7 = fmaf(a7 + bf2f(sv.w >> 16),     dn, loadf(b, 8 * f8 + 7, F32));
        if (do_relu) {
            v0 = fmaxf(v0, 0.f); v1 = fmaxf(v1, 0.f); v2 = fmaxf(v2, 0.f); v3 = fmaxf(v3, 0.f);
            v4 = fmaxf(v4, 0.f); v5 = fmaxf(v5, 0.f); v6 = fmaxf(v6, 0.f); v7 = fmaxf(v7, 0.f);
        }
        uint4 o;
        o.x = f2bf(v0) | ((unsigned int)f2bf(v1) << 16);
        o.y = f2bf(v2) | ((unsigned int)f2bf(v3) << 16);
        o.z = f2bf(v4) | ((unsigned int)f2bf(v5) << 16);
        o.w = f2bf(v6) | ((unsigned int)f2bf(v7) << 16);
        ((uint4*)out)[(size_t)node * 8 + f8] = o;
    }
}

// ---------------- fused mean-pool + linear head (bf16 h, gptr ranges) ---------
__global__ void k_pool_final(const int* __restrict__ gptr,
                             const unsigned short* __restrict__ h,
                             const void* __restrict__ Wl, const void* __restrict__ bl,
                             void* __restrict__ out, const int* __restrict__ flags) {
    int F32 = flags[0];
    int g = blockIdx.x;
    int lane = threadIdx.x;  // 64
    int s = gptr[g], e = gptr[g + 1];
    float acc = 0.0f;
    for (int n = s; n < e; ++n) acc += bf2f(h[(size_t)n * HID + lane]);
    float cnt = fmaxf((float)(e - s), 1.0f);
    float v = (acc / cnt) * loadf(Wl, lane, F32);
#pragma unroll
    for (int o = 32; o > 0; o >>= 1) v += __shfl_down(v, o, 64);
    if (lane == 0) {
        float r = v + loadf(bl, 0, F32);
        if (F32) ((float*)out)[g] = r;
        else     ((__hip_bfloat16*)out)[g] = __float2bfloat16(r);
    }
}

extern "C" void kernel_launch(void* const* d_in, const int* in_sizes, int n_in,
                              void* d_out, int out_size, void* d_ws, size_t ws_size,
                              hipStream_t stream) {
    const void* x     = d_in[0];
    const void* ei    = d_in[1];
    const void* batch = d_in[2];
    const void* W1 = d_in[3];
    const void* b1 = d_in[4];
    const void* W2 = d_in[5];
    const void* b2 = d_in[6];
    const void* W3 = d_in[7];
    const void* b3 = d_in[8];
    const void* Wl = d_in[9];
    const void* bl = d_in[10];

    // workspace layout (~41 MB)
    float* dis   = (float*)d_ws;             // 100352
    int*   cnt   = (int*)(dis + 100352);     // 100352
    int*   rp    = cnt + 100352;             // 100352 (needs 100001)
    int*   csr   = rp + 100352;              // 1600000
    int*   gcnt  = csr + 1600000;            // 1024
    int*   gptr  = gcnt + 1024;              // 1056 (needs 1025)
    int*   partN = gptr + 1056;              // 512
    int*   bcnt  = partN + 512;              // 256
    int*   flags = bcnt + 256;               // 16
    unsigned int* packed = (unsigned int*)(flags + 16);    // NB*BCAP (7.8 MB)
    unsigned short* bufA = (unsigned short*)(packed + (size_t)NB * BCAP);  // bf16 xws (12.8 MB)
    unsigned short* bufB = bufA + 6400000;                 // bf16 h (12.8 MB)

    const int TB = 256;
    dim3 blk(TB);
    int gN  = (N_NODES + TB - 1) / TB;       // 391
    int gG4 = (N_NODES + 3) / 4;             // 25000 (gather blocks)

    // init: detect + zero small counters
    k_init<<<1, blk, 0, stream>>>((const unsigned int*)x, (const unsigned int*)ei,
                                  flags, gcnt, bcnt);
    // phase A partition (+ batch counts)
    k_part<<<(N_EDGES + 1023) / 1024, blk, 0, stream>>>(ei, batch, bcnt, gcnt, packed, flags);
    // hist: cnt + dis + scan partials
    k_hist<<<NBU, blk, 0, stream>>>(packed, bcnt, cnt, dis, partN);
    // middle scan: partN exclusive + rp[N] + graph scan -> gptr
    k_scan_mid<<<1, 512, 0, stream>>>(partN, gN, rp, N_NODES, gcnt, gptr);
    // p3: rp
    k_scan_p3<<<gN, blk, 0, stream>>>(cnt, partN, rp, N_NODES);
    // phase B: dense csr
    k_bucketcsr<<<NBU, 512, 0, stream>>>(packed, bcnt, rp, csr);

    // ---- layer 1 ----
    k_gemm<F_IN><<<1024, blk, 0, stream>>>(x, W1, dis, bufA, flags, -1);
    k_gather<<<gG4, blk, 0, stream>>>(rp, csr, dis, bufA, b1, bufB, 1, flags);
    // ---- layer 2 ----
    k_gemm<HID><<<1024, blk, 0, stream>>>(bufB, W2, dis, bufA, flags, 0);
    k_gather<<<gG4, blk, 0, stream>>>(rp, csr, dis, bufA, b2, bufB, 1, flags);
    // ---- layer 3 ----
    k_gemm<HID><<<1024, blk, 0, stream>>>(bufB, W3, dis, bufA, flags, 0);
    k_gather<<<gG4, blk, 0, stream>>>(rp, csr, dis, bufA, b3, bufB, 0, flags);

    // ---- pool + head ----
    k_pool_final<<<N_GRAPHS, 64, 0, stream>>>(gptr, bufB, Wl, bl, d_out, flags);
}

// Round 14
// 398.605 us; speedup vs baseline: 2.0307x; 1.0773x over previous
//
#include <hip/hip_runtime.h>
#include <hip/hip_bf16.h>

#define N_NODES 100000
#define N_EDGES 1600000
#define F_IN 128
#define HID 64
#define N_GRAPHS 1024

// fine dst-partition for CSR build: bucket = dst>>9 (512 nodes/bucket)
#define SH 9
#define NBU 196        // buckets used: ceil(100000/512)
#define NB 200         // allocated
#define BCAP 9728      // mean 8192 + 17 sigma
#define EPB 8192       // edges per k_part block (196 blocks exactly)

typedef __attribute__((ext_vector_type(8))) short bf16x8;
typedef __attribute__((ext_vector_type(4))) float f32x4;
typedef __attribute__((ext_vector_type(4))) unsigned int u32x4;

// ---------------- bf16 bit helpers --------------------------------------------
__device__ __forceinline__ unsigned short f2bf(float f) {
    __hip_bfloat16 h = __float2bfloat16(f);   // RNE
    return *reinterpret_cast<unsigned short*>(&h);
}
__device__ __forceinline__ float bf2f(unsigned int u) {
    return __uint_as_float(u << 16);
}

// ---------------- dual-path load helpers (wire dtype resolved at runtime) -----
__device__ __forceinline__ float loadf(const void* p, size_t i, int f32) {
    if (f32) return ((const float*)p)[i];
    return __bfloat162float(((const __hip_bfloat16*)p)[i]);
}
__device__ __forceinline__ int loadi(const void* p, size_t i, int i64) {
    if (i64) return (int)((const long long*)p)[i];
    return ((const int*)p)[i];
}

// ---------------- init: wire detect + zero small counters ---------------------
__global__ void k_init(const unsigned int* __restrict__ xw_,
                       const unsigned int* __restrict__ ei_,
                       int* __restrict__ flags,
                       int* __restrict__ gcnt, int* __restrict__ bcnt) {
    __shared__ int cnt_f, cnt_i;
    int t = threadIdx.x;
    if (t == 0) { cnt_f = 0; cnt_i = 0; }
    __syncthreads();
    unsigned int w = xw_[t];
    unsigned int e = (w >> 7) & 0xFFu;
    if (e >= 100u && e <= 140u) atomicAdd(&cnt_f, 1);
    unsigned int iw = ei_[2 * t + 1];
    if (iw == 0u) atomicAdd(&cnt_i, 1);
    for (int i = t; i < N_GRAPHS; i += 256) gcnt[i] = 0;
    for (int i = t; i < NB; i += 256) bcnt[i] = 0;
    __syncthreads();
    if (t == 0) {
        flags[0] = (cnt_f < 180) ? 1 : 0;   // 1 => fp32 wire
        flags[1] = (cnt_i >= 128) ? 1 : 0;  // 1 => int64 wire
    }
}

// ---------------- phase A: partition by dst>>9, two-pass fat blocks -----------
// 196 blocks x 8192 edges. Pass 1: LDS bucket counts -> ONE global reserve per
// bucket per block (R13: 1563-block version serialized on 200 global counters,
// chain 1563 x ~150cyc = 63 us; 196 blocks cuts the chain 8x). Pass 2: re-read
// edges (L3-hot), re-rank via zeroed LDS hist, write packed. Batch counts
// pre-aggregated in a 1024-bin LDS hist (kills sorted-batch same-address
// global-atomic serialization). PLAIN stores (NT partial lines = R10 regression).
__global__ __launch_bounds__(256) void k_part(const void* __restrict__ ei,
                                              const void* __restrict__ batch,
                                              int* __restrict__ bcnt,
                                              int* __restrict__ gcnt,
                                              unsigned int* __restrict__ packed,
                                              const int* __restrict__ flags) {
    int I64 = flags[1];
    __shared__ int hist[NB];
    __shared__ int base[NB];
    __shared__ int ghist[N_GRAPHS];   // 4 KB
    int t = threadIdx.x;
    if (t < NB) hist[t] = 0;
    for (int i = t; i < N_GRAPHS; i += 256) ghist[i] = 0;
    __syncthreads();
    // batch counting: block covers nodes [blk*512, blk*512+512)
    for (int it = 0; it < 2; ++it) {
        int n = blockIdx.x * 512 + it * 256 + t;
        if (n < N_NODES) atomicAdd(&ghist[loadi(batch, n, I64)], 1);
    }
    // edge pass 1: bucket counts
    int e0 = blockIdx.x * EPB;
#pragma unroll 4
    for (int it = 0; it < EPB / 256; ++it) {
        int e = e0 + it * 256 + t;
        if (e < N_EDGES) {
            int d = loadi(ei, (size_t)N_EDGES + e, I64);
            atomicAdd(&hist[d >> SH], 1);
        }
    }
    __syncthreads();
    if (t < NB) {
        base[t] = hist[t] ? atomicAdd(&bcnt[t], hist[t]) : 0;
        hist[t] = 0;   // reuse as pass-2 rank counter
    }
    for (int i = t; i < N_GRAPHS; i += 256)
        if (ghist[i]) atomicAdd(&gcnt[i], ghist[i]);
    __syncthreads();
    // edge pass 2: rank + write
#pragma unroll 4
    for (int it = 0; it < EPB / 256; ++it) {
        int e = e0 + it * 256 + t;
        if (e < N_EDGES) {
            int s = loadi(ei, e, I64);
            int d = loadi(ei, (size_t)N_EDGES + e, I64);
            int b = d >> SH;
            int r = atomicAdd(&hist[b], 1);
            int pos = base[b] + r;
            if (pos < BCAP)
                packed[(size_t)b * BCAP + pos] = ((unsigned int)s << SH) | (unsigned int)(d & 511);
        }
    }
}

// ---------------- hist: in-degree + dis + scan partials (fused) ---------------
__global__ __launch_bounds__(256) void k_hist(const unsigned int* __restrict__ packed,
                                              const int* __restrict__ bcnt,
                                              int* __restrict__ cnt,
                                              float* __restrict__ dis,
                                              int* __restrict__ partN) {
    __shared__ int hist[512];
    int b = blockIdx.x;
    int t = threadIdx.x;
    int n = bcnt[b];
    if (n > BCAP) n = BCAP;
    for (int i = t; i < 512; i += 256) hist[i] = 0;
    __syncthreads();
    const unsigned int* pb = packed + (size_t)b * BCAP;
    for (int i = t; i < n; i += 256)
        atomicAdd(&hist[pb[i] & 511u], 1);
    __syncthreads();
    int nbase = b << SH;
    for (int i = t; i < 512; i += 256) {
        int node = nbase + i;
        if (node < N_NODES) {
            int c = hist[i];
            cnt[node] = c;
            dis[node] = rsqrtf((float)c + 1.0f);
        }
    }
    __syncthreads();
    for (int off = 128; off > 0; off >>= 1) {
        if (t < off) { hist[t] += hist[t + off]; hist[256 + t] += hist[256 + t + off]; }
        __syncthreads();
    }
    if (t == 0) {
        partN[2 * b] = hist[0];
        if (2 * b + 1 < 391) partN[2 * b + 1] = hist[256];
    }
}

// ---------------- middle scan: partN (391) + graph scan (1024), one block -----
__global__ void k_scan_mid(int* __restrict__ partial, int nb,
                           int* __restrict__ rp, int n,
                           const int* __restrict__ gcnt, int* __restrict__ gptr) {
    __shared__ int s[512];
    int t = threadIdx.x;
    int v = (t < nb) ? partial[t] : 0;
    s[t] = v;
    __syncthreads();
    for (int off = 1; off < 512; off <<= 1) {
        int x = (t >= off) ? s[t - off] : 0;
        __syncthreads();
        s[t] += x;
        __syncthreads();
    }
    if (t < nb) partial[t] = s[t] - v;   // exclusive
    if (t == 511) rp[n] = s[511];        // grand total
    __syncthreads();
    int a = gcnt[2 * t], bq = gcnt[2 * t + 1];
    int ps = a + bq;
    s[t] = ps;
    __syncthreads();
    for (int off = 1; off < 512; off <<= 1) {
        int x = (t >= off) ? s[t - off] : 0;
        __syncthreads();
        s[t] += x;
        __syncthreads();
    }
    int excl = s[t] - ps;
    gptr[2 * t] = excl;
    gptr[2 * t + 1] = excl + a;
    if (t == 511) gptr[1024] = s[511];
}

// ---------------- scan p3: per-256-chunk local scan + offset -> rp ------------
__global__ void k_scan_p3(const int* __restrict__ in, const int* __restrict__ partial,
                          int* __restrict__ out, int n) {
    __shared__ int s[256];
    int t = threadIdx.x;
    int i = blockIdx.x * 256 + t;
    int v = (i < n) ? in[i] : 0;
    s[t] = v;
    __syncthreads();
    for (int off = 1; off < 256; off <<= 1) {
        int x = (t >= off) ? s[t - off] : 0;
        __syncthreads();
        s[t] += x;
        __syncthreads();
    }
    if (i < n) out[i] = partial[blockIdx.x] + s[t] - v;
}

// ---------------- phase B: LDS counting-sort, dense csr writes ----------------
__global__ __launch_bounds__(512) void k_bucketcsr(const unsigned int* __restrict__ packed,
                                                   const int* __restrict__ bcnt,
                                                   const int* __restrict__ rp,
                                                   int* __restrict__ csr) {
    __shared__ int offs[512];
    __shared__ int elds[BCAP];    // 38 KB
    int b = blockIdx.x;
    int nbase = b << SH;
    int base = rp[nbase];
    int lim = nbase + 512; if (lim > N_NODES) lim = N_NODES;
    int nedge = rp[lim] - base;
    if (nedge > BCAP) nedge = BCAP;
    for (int i = threadIdx.x; i < 512; i += 512) {
        int node = nbase + i;
        offs[i] = (node < N_NODES) ? (rp[node] - base) : nedge;
    }
    __syncthreads();
    int n = bcnt[b]; if (n > BCAP) n = BCAP;
    const unsigned int* pb = packed + (size_t)b * BCAP;
    for (int i = threadIdx.x; i < n; i += 512) {
        unsigned int p = pb[i];
        int pos = atomicAdd(&offs[p & 511u], 1);
        if (pos < BCAP) elds[pos] = (int)(p >> SH);
    }
    __syncthreads();
    for (int i = threadIdx.x; i < nedge; i += 512)
        csr[base + i] = elds[i];
}

// ---------------- MFMA GEMM: in[N,K] @ W[K,64] -> out[N,64] bf16, x dis[row] --
template <int K>
__global__ __launch_bounds__(256) void k_gemm(const void* __restrict__ x,
                                              const void* __restrict__ W,
                                              const float* __restrict__ dis,
                                              unsigned short* __restrict__ out,  // bf16 bits
                                              const int* __restrict__ flags,
                                              int x_is_f32) {
    int Wf32 = flags[0];
    int xF32 = (x_is_f32 < 0) ? Wf32 : x_is_f32;
    __shared__ unsigned short Wt[64][K + 8];
    __shared__ unsigned short xs[32][K + 8];
    int t = threadIdx.x;
    int wave = t >> 6, lane = t & 63;
    int quad = lane >> 4, l16 = lane & 15;

    for (int id = t; id < 64 * K; id += 256) {
        int k = id >> 6, n = id & 63;
        Wt[n][k] = f2bf(loadf(W, id, Wf32));
    }
    __syncthreads();

    bf16x8 bfrag[K / 32];
#pragma unroll
    for (int c = 0; c < K / 32; ++c)
        bfrag[c] = *reinterpret_cast<bf16x8*>(&Wt[wave * 16 + l16][c * 32 + quad * 8]);

    const int ngroups = (N_NODES + 31) / 32;
    for (int g = blockIdx.x; g < ngroups; g += gridDim.x) {
        __syncthreads();
        int row0 = g * 32;
        for (int cid = t; cid < 4 * K; cid += 256) {
            int rr = cid / (K / 8), c8 = cid % (K / 8);
            int r = row0 + rr;
            u32x4 val = {0u, 0u, 0u, 0u};
            if (r < N_NODES) {
                size_t base = (size_t)r * K + c8 * 8;
                if (xF32) {
                    const u32x4* xp = (const u32x4*)x;
                    u32x4 q0 = xp[base / 4];
                    u32x4 q1 = xp[base / 4 + 1];
                    val.x = f2bf(__uint_as_float(q0.x)) | ((unsigned int)f2bf(__uint_as_float(q0.y)) << 16);
                    val.y = f2bf(__uint_as_float(q0.z)) | ((unsigned int)f2bf(__uint_as_float(q0.w)) << 16);
                    val.z = f2bf(__uint_as_float(q1.x)) | ((unsigned int)f2bf(__uint_as_float(q1.y)) << 16);
                    val.w = f2bf(__uint_as_float(q1.z)) | ((unsigned int)f2bf(__uint_as_float(q1.w)) << 16);
                } else {
                    val = ((const u32x4*)x)[base / 8];
                }
            }
            *reinterpret_cast<u32x4*>(&xs[rr][c8 * 8]) = val;
        }
        __syncthreads();

        f32x4 acc0 = {0.f, 0.f, 0.f, 0.f};
        f32x4 acc1 = {0.f, 0.f, 0.f, 0.f};
#pragma unroll
        for (int c = 0; c < K / 32; ++c) {
            bf16x8 a0 = *reinterpret_cast<bf16x8*>(&xs[l16][c * 32 + quad * 8]);
            bf16x8 a1 = *reinterpret_cast<bf16x8*>(&xs[16 + l16][c * 32 + quad * 8]);
            acc0 = __builtin_amdgcn_mfma_f32_16x16x32_bf16(a0, bfrag[c], acc0, 0, 0, 0);
            acc1 = __builtin_amdgcn_mfma_f32_16x16x32_bf16(a1, bfrag[c], acc1, 0, 0, 0);
        }
        int col = wave * 16 + l16;
#pragma unroll
        for (int reg = 0; reg < 4; ++reg) {
            int r0 = row0 + quad * 4 + reg;
            if (r0 < N_NODES) out[(size_t)r0 * 64 + col] = f2bf(acc0[reg] * dis[r0]);
            int r1 = row0 + 16 + quad * 4 + reg;
            if (r1 < N_NODES) out[(size_t)r1 * 64 + col] = f2bf(acc1[reg] * dis[r1]);
        }
    }
}

// ---------------- fused gather + self-loop + bias + relu (bf16 in/out) --------
__global__ __launch_bounds__(256) void k_gather(const int* __restrict__ rp,
                                                const int* __restrict__ csr,
                                                const float* __restrict__ dis,
                                                const unsigned short* __restrict__ xws,
                                                const void* __restrict__ b,
                                                unsigned short* __restrict__ out,
                                                int do_relu,
                                                const int* __restrict__ flags) {
    int F32 = flags[0];
    int wave = threadIdx.x >> 6, lane = threadIdx.x & 63;
    int node = blockIdx.x * 4 + wave;
    if (node >= N_NODES) return;
    int f8 = lane & 7, nsub = lane >> 3;
    int start = rp[node], end = rp[node + 1];
    const uint4* x8 = (const uint4*)xws;   // row = 8 uint4 (128 B)
    float a0 = 0, a1 = 0, a2 = 0, a3 = 0, a4 = 0, a5 = 0, a6 = 0, a7 = 0;
    int j = start + nsub;
    if (j < end) {
        int s = csr[j];
        for (;;) {
            int jn = j + 8;
            int sn = (jn < end) ? csr[jn] : 0;     // prefetch next index
            uint4 v = x8[(size_t)s * 8 + f8];
            a0 += bf2f(v.x & 0xFFFFu); a1 += bf2f(v.x >> 16);
            a2 += bf2f(v.y & 0xFFFFu); a3 += bf2f(v.y >> 16);
            a4 += bf2f(v.z & 0xFFFFu); a5 += bf2f(v.z >> 16);
            a6 += bf2f(v.w & 0xFFFFu); a7 += bf2f(v.w >> 16);
            if (jn >= end) break;
            j = jn; s = sn;
        }
    }
#pragma unroll
    for (int off = 32; off >= 8; off >>= 1) {
        a0 += __shfl_down(a0, off, 64); a1 += __shfl_down(a1, off, 64);
        a2 += __shfl_down(a2, off, 64); a3 += __shfl_down(a3, off, 64);
        a4 += __shfl_down(a4, off, 64); a5 += __shfl_down(a5, off, 64);
        a6 += __shfl_down(a6, off, 64); a7 += __shfl_down(a7, off, 64);
    }
    if (nsub == 0) {
        uint4 sv = x8[(size_t)node * 8 + f8];
        float dn = dis[node];
        float v0 = fmaf(a0 + bf2f(sv.x & 0xFFFFu), dn, loadf(b, 8 * f8 + 0, F32));
        float v1 = fmaf(a1 + bf2f(sv.x >> 16),     dn, loadf(b, 8 * f8 + 1, F32));
        float v2 = fmaf(a2 + bf2f(sv.y & 0xFFFFu), dn, loadf(b, 8 * f8 + 2, F32));
        float v3 = fmaf(a3 + bf2f(sv.y >> 16),     dn, loadf(b, 8 * f8 + 3, F32));
        float v4 = fmaf(a4 + bf2f(sv.z & 0xFFFFu), dn, loadf(b, 8 * f8 + 4, F32));
        float v5 = fmaf(a5 + bf2f(sv.z >> 16),     dn, loadf(b, 8 * f8 + 5, F32));
        float v6 = fmaf(a6 + bf2f(sv.w & 0xFFFFu), dn, loadf(b, 8 * f8 + 6, F32));
        float v7 = fmaf(a7 + bf2f(sv.w >> 16),     dn, loadf(b, 8 * f8 + 7, F32));
        if (do_relu) {
            v0 = fmaxf(v0, 0.f); v1 = fmaxf(v1, 0.f); v2 = fmaxf(v2, 0.f); v3 = fmaxf(v3, 0.f);
            v4 = fmaxf(v4, 0.f); v5 = fmaxf(v5, 0.f); v6 = fmaxf(v6, 0.f); v7 = fmaxf(v7, 0.f);
        }
        uint4 o;
        o.x = f2bf(v0) | ((unsigned int)f2bf(v1) << 16);
        o.y = f2bf(v2) | ((unsigned int)f2bf(v3) << 16);
        o.z = f2bf(v4) | ((unsigned int)f2bf(v5) << 16);
        o.w = f2bf(v6) | ((unsigned int)f2bf(v7) << 16);
        ((uint4*)out)[(size_t)node * 8 + f8] = o;
    }
}

// ---------------- fused mean-pool + linear head (4 graphs/block) --------------
__global__ __launch_bounds__(256) void k_pool_final(const int* __restrict__ gptr,
                             const unsigned short* __restrict__ h,
                             const void* __restrict__ Wl, const void* __restrict__ bl,
                             void* __restrict__ out, const int* __restrict__ flags) {
    int F32 = flags[0];
    int g = blockIdx.x * 4 + (threadIdx.x >> 6);
    int lane = threadIdx.x & 63;
    if (g >= N_GRAPHS) return;
    int s = gptr[g], e = gptr[g + 1];
    float acc = 0.0f;
    for (int n = s; n < e; ++n) acc += bf2f(h[(size_t)n * HID + lane]);
    float cnt = fmaxf((float)(e - s), 1.0f);
    float v = (acc / cnt) * loadf(Wl, lane, F32);
#pragma unroll
    for (int o = 32; o > 0; o >>= 1) v += __shfl_down(v, o, 64);
    if (lane == 0) {
        float r = v + loadf(bl, 0, F32);
        if (F32) ((float*)out)[g] = r;
        else     ((__hip_bfloat16*)out)[g] = __float2bfloat16(r);
    }
}

extern "C" void kernel_launch(void* const* d_in, const int* in_sizes, int n_in,
                              void* d_out, int out_size, void* d_ws, size_t ws_size,
                              hipStream_t stream) {
    const void* x     = d_in[0];
    const void* ei    = d_in[1];
    const void* batch = d_in[2];
    const void* W1 = d_in[3];
    const void* b1 = d_in[4];
    const void* W2 = d_in[5];
    const void* b2 = d_in[6];
    const void* W3 = d_in[7];
    const void* b3 = d_in[8];
    const void* Wl = d_in[9];
    const void* bl = d_in[10];

    // workspace layout (~41 MB)
    float* dis   = (float*)d_ws;             // 100352
    int*   cnt   = (int*)(dis + 100352);     // 100352
    int*   rp    = cnt + 100352;             // 100352 (needs 100001)
    int*   csr   = rp + 100352;              // 1600000
    int*   gcnt  = csr + 1600000;            // 1024
    int*   gptr  = gcnt + 1024;              // 1056 (needs 1025)
    int*   partN = gptr + 1056;              // 512
    int*   bcnt  = partN + 512;              // 256
    int*   flags = bcnt + 256;               // 16
    unsigned int* packed = (unsigned int*)(flags + 16);    // NB*BCAP (7.8 MB)
    unsigned short* bufA = (unsigned short*)(packed + (size_t)NB * BCAP);  // bf16 xws (12.8 MB)
    unsigned short* bufB = bufA + 6400000;                 // bf16 h (12.8 MB)

    const int TB = 256;
    dim3 blk(TB);
    int gN  = (N_NODES + TB - 1) / TB;       // 391
    int gG4 = (N_NODES + 3) / 4;             // 25000 (gather blocks)

    // init: detect + zero small counters
    k_init<<<1, blk, 0, stream>>>((const unsigned int*)x, (const unsigned int*)ei,
                                  flags, gcnt, bcnt);
    // phase A partition (two-pass fat blocks, + batch counts)
    k_part<<<(N_EDGES + EPB - 1) / EPB, blk, 0, stream>>>(ei, batch, bcnt, gcnt, packed, flags);
    // hist: cnt + dis + scan partials
    k_hist<<<NBU, blk, 0, stream>>>(packed, bcnt, cnt, dis, partN);
    // middle scan: partN exclusive + rp[N] + graph scan -> gptr
    k_scan_mid<<<1, 512, 0, stream>>>(partN, gN, rp, N_NODES, gcnt, gptr);
    // p3: rp
    k_scan_p3<<<gN, blk, 0, stream>>>(cnt, partN, rp, N_NODES);
    // phase B: dense csr
    k_bucketcsr<<<NBU, 512, 0, stream>>>(packed, bcnt, rp, csr);

    // ---- layer 1 ----
    k_gemm<F_IN><<<1024, blk, 0, stream>>>(x, W1, dis, bufA, flags, -1);
    k_gather<<<gG4, blk, 0, stream>>>(rp, csr, dis, bufA, b1, bufB, 1, flags);
    // ---- layer 2 ----
    k_gemm<HID><<<1024, blk, 0, stream>>>(bufB, W2, dis, bufA, flags, 0);
    k_gather<<<gG4, blk, 0, stream>>>(rp, csr, dis, bufA, b2, bufB, 1, flags);
    // ---- layer 3 ----
    k_gemm<HID><<<1024, blk, 0, stream>>>(bufB, W3, dis, bufA, flags, 0);
    k_gather<<<gG4, blk, 0, stream>>>(rp, csr, dis, bufA, b3, bufB, 0, flags);

    // ---- pool + head ----
    k_pool_final<<<N_GRAPHS / 4, blk, 0, stream>>>(gptr, bufB, Wl, bl, d_out, flags);
}